// Round 9
// baseline (322.002 us; speedup 1.0000x reference)
//
#include <hip/hip_runtime.h>
#include <hip/hip_fp16.h>
#include <stdint.h>

constexpr int N_NODES = 50000;
constexpr int N_EDGES = 800000;
constexpr int HD      = 128;
constexpr int NREL    = 8;
constexpr int NBUCK   = N_NODES * NREL;   // 400000 (dst,etype) buckets

typedef unsigned short ushortT;
using bf16x8 = __attribute__((ext_vector_type(8))) short;
using f32x4  = __attribute__((ext_vector_type(4))) float;

typedef const __attribute__((address_space(1))) void* gptr_t;
typedef __attribute__((address_space(3))) void* lptr_t;

__device__ __forceinline__ float b2f(uint32_t lo16){
  uint32_t x = lo16 << 16; float f; __builtin_memcpy(&f,&x,4); return f;
}
__device__ __forceinline__ uint16_t f2b(float f){
  uint32_t x; __builtin_memcpy(&x,&f,4);
  uint32_t r = (x + 0x7FFFu + ((x>>16)&1u)) >> 16;
  return (uint16_t)r;
}

// ---------------- CSR build over (dst*8+etype) buckets ----------------
__global__ void k_hist(const int* __restrict__ dst, const int* __restrict__ et,
                       int* __restrict__ deg){
  int i = blockIdx.x*blockDim.x + threadIdx.x;
  if(i<N_EDGES) atomicAdd(&deg[dst[i]*NREL + et[i]],1);
}

__global__ void k_scan1(const int* __restrict__ in, int* __restrict__ out,
                        int* __restrict__ part, int n){
  __shared__ int sm[256];
  int t = threadIdx.x; int i = blockIdx.x*256+t;
  int v = (i<n)? in[i] : 0;
  sm[t]=v; __syncthreads();
  for(int off=1; off<256; off<<=1){
    int x = (t>=off)? sm[t-off] : 0;
    __syncthreads();
    sm[t]+=x;
    __syncthreads();
  }
  if(i<n) out[i]=sm[t]-v;       // exclusive within block
  if(t==255) part[blockIdx.x]=sm[255];
}

// single-block chunked scan of the partials
__global__ void k_scanmid(int* __restrict__ part, int n){
  __shared__ int sm[256];
  __shared__ int carry;
  int t=threadIdx.x;
  if(t==0) carry=0;
  __syncthreads();
  for(int base=0; base<n; base+=256){
    int i=base+t;
    int v=(i<n)? part[i] : 0;
    sm[t]=v; __syncthreads();
    for(int off=1; off<256; off<<=1){
      int x=(t>=off)? sm[t-off] : 0;
      __syncthreads();
      sm[t]+=x;
      __syncthreads();
    }
    int tot = sm[255];
    if(i<n) part[i]=sm[t]-v+carry;
    __syncthreads();
    if(t==0) carry += tot;
    __syncthreads();
  }
}

// edge record: src in low 16 bits, fp16 weight in high 16 bits (4B total)
// bucket base = offs[b] (block-local) + part1[b>>8] (block offsets)
__global__ void k_scatter(const int* __restrict__ src, const int* __restrict__ et,
                          const float* __restrict__ w, const int* __restrict__ dst,
                          const int* __restrict__ offs, const int* __restrict__ part,
                          int* __restrict__ cur, uint32_t* __restrict__ es){
  int i = blockIdx.x*blockDim.x + threadIdx.x;
  if(i<N_EDGES){
    int b = dst[i]*NREL + et[i];
    int pos = offs[b] + part[b>>8] + atomicAdd(&cur[b],1);
    __half h = __float2half(w[i]);
    ushortT hb; __builtin_memcpy(&hb,&h,2);
    es[pos] = (uint32_t)(src[i] & 0xFFFF) | ((uint32_t)hb << 16);
  }
}

// ---------------- fused prep: f2b table convert + relation weights --------
constexpr int F2B_BLOCKS = (N_NODES*HD/4 + 255)/256;   // 6250
__global__ void k_prep(const float* __restrict__ feat,
                       const float* __restrict__ comp1, const float* __restrict__ V1,
                       const float* __restrict__ comp2, const float* __restrict__ V2,
                       ushortT* __restrict__ xb,
                       ushortT* __restrict__ Wt1, ushortT* __restrict__ Wt2){
  if(blockIdx.x < F2B_BLOCKS){
    int i = blockIdx.x*256 + threadIdx.x;
    if(i < N_NODES*HD/4){
      float4 v = ((const float4*)feat)[i];
      ushort4 o;
      o.x=f2b(v.x); o.y=f2b(v.y); o.z=f2b(v.z); o.w=f2b(v.w);
      ((ushort4*)xb)[i]=o;
    }
  } else {
    int t = (blockIdx.x - F2B_BLOCKS)*256 + threadIdx.x;   // 0..262143
    int layer = t >> 17;
    t &= 131071;
    const float* comp = layer? comp2 : comp1;
    const float* V    = layer? V2    : V1;
    ushortT* Wt       = layer? Wt2   : Wt1;
    int o  = t >> 10;                // 0..127
    int rk = t & 1023;
    int r  = rk >> 7, k = rk & 127;
    float s=0.f;
    #pragma unroll
    for(int b=0;b<NREL;b++) s += comp[r*NREL+b]*V[(b<<14) + k*HD + o];
    Wt[t]=f2b(s);
  }
}

// ---------------- aggregate-first: 4 buckets per WAVE ----------------
// lane = q*16+f : quarter q owns bucket wave*4+q, lane f covers bytes [f*16,f*16+16)
// Acat[b][128] bf16, b = node*8+r  (== A[node][1024] r-major)
__global__ void __launch_bounds__(256)
k_agg(const ushortT* __restrict__ xb,   // [N][128] bf16 gather table
      const int* __restrict__ offs, const int* __restrict__ part,
      const int* __restrict__ deg,
      const uint32_t* __restrict__ es,  // packed (src u16, w fp16)
      ushortT* __restrict__ Acat){
  int wave = blockIdx.x*4 + (threadIdx.x>>6);
  int lane = threadIdx.x & 63;
  int q = lane >> 4, f = lane & 15;
  int b = wave*4 + q;                   // grid sized exactly: NBUCK/4 waves
  int beg = offs[b] + part[b>>8], cnt = deg[b];
  const uint32_t* ep = es + beg;
  float a[8] = {};
  uint32_t e = 0;
  if(cnt > 0) e = ep[0];                // masked prefetch
  for(int j=0;j<cnt;j++){
    uint32_t ce = e;
    if(j+1 < cnt) e = ep[j+1];          // prefetch next edge while gathering
    ushortT hb = (ushortT)(ce >> 16);
    __half h; __builtin_memcpy(&h,&hb,2);
    float w = __half2float(h);
    int s = (int)(ce & 0xFFFFu);
    bf16x8 v = *(const bf16x8*)&xb[(size_t)s*HD + f*8];
    #pragma unroll
    for(int t=0;t<8;t++) a[t] += w * b2f((uint16_t)v[t]);
  }
  uint32_t pk[4];
  #pragma unroll
  for(int i=0;i<4;i++)
    pk[i] = (uint32_t)f2b(a[2*i]) | ((uint32_t)f2b(a[2*i+1])<<16);
  // wave writes 4 adjacent 256B rows -> 1KB contiguous
  *(uint4*)&Acat[(size_t)b*HD + f*8] = *(uint4*)pk;
}

// ---------------- high-occupancy MFMA GEMM: out[M][128] = A[M][1024] @ Wt^T ----
// BM=32 -> 1563 blocks (6.1/CU). A via global_load_lds(16B) + XOR chunk-swizzle,
// 8KB double-buffered LDS. B (L2-hot 256KB) straight to registers.
constexpr int GBM=32, GBK=64;
__global__ void __launch_bounds__(256)
k_gemm(const ushortT* __restrict__ A,   // [M+pad][1024] bf16
       const ushortT* __restrict__ Wt,  // [128][1024] bf16 (B^T, o-major)
       const float* __restrict__ bias,
       float* __restrict__ outF,        // layer2 output (f32) or null
       ushortT* __restrict__ outB,      // layer1 output (bf16) or null
       int relu){
  __shared__ ushortT Asm[2][GBM][GBK];   // 8 KB
  int tid = threadIdx.x;
  int wid = tid>>6, lane = tid&63;
  int l15 = lane&15, lhi = lane>>4;
  int row0 = blockIdx.x*GBM;
  int wc = wid*32;                       // wave owns all 32 rows x cols wc..wc+31
  int srow = lane>>3, schunk = lane&7;   // staging: wave covers rows wid*8..+7
  int gc = schunk ^ (srow&7);            // inverse swizzle on SOURCE
  const ushortT* gsrc = A + (size_t)(row0 + wid*8 + srow)*1024 + gc*8;

  auto stage = [&](int buf, int kt){
    __builtin_amdgcn_global_load_lds((gptr_t)(gsrc + kt),
        (lptr_t)&Asm[buf][wid*8][0], 16, 0, 0);
  };

  f32x4 acc[2][2] = {};
  stage(0, 0);
  asm volatile("s_waitcnt vmcnt(0)" ::: "memory");
  __syncthreads();

  for(int t=0;t<16;t++){
    int cur = t & 1;
    // B fragments for this step, straight from L2-hot Wt
    bf16x8 bfr[2][2];
    #pragma unroll
    for(int kk=0;kk<2;kk++)
      #pragma unroll
      for(int n=0;n<2;n++)
        bfr[kk][n] = *(const bf16x8*)&Wt[(size_t)(wc + n*16 + l15)*1024
                                         + t*GBK + kk*32 + lhi*8];
    if(t+1 < 16) stage(cur^1, (t+1)*GBK);   // prefetch under compute
    #pragma unroll
    for(int kk=0;kk<2;kk++){
      bf16x8 af[2];
      #pragma unroll
      for(int m=0;m<2;m++){
        int r = m*16 + l15;
        int c = (kk*4 + lhi) ^ (r&7);       // swizzled read
        af[m] = *(const bf16x8*)&Asm[cur][r][c*8];
      }
      #pragma unroll
      for(int m=0;m<2;m++)
        #pragma unroll
        for(int n=0;n<2;n++)
          acc[m][n] = __builtin_amdgcn_mfma_f32_16x16x32_bf16(af[m], bfr[kk][n], acc[m][n], 0,0,0);
    }
    asm volatile("s_waitcnt vmcnt(0)" ::: "memory");   // prefetch landed
    __syncthreads();
  }

  // epilogue: D row=lhi*4+j, col=l15 per 16x16 fragment
  #pragma unroll
  for(int m=0;m<2;m++){
    #pragma unroll
    for(int j=0;j<4;j++){
      int grow = row0 + m*16 + lhi*4 + j;
      if(grow < N_NODES){
        #pragma unroll
        for(int n=0;n<2;n++){
          int col = wc + n*16 + l15;
          float v = acc[m][n][j] + bias[col];
          if(relu) v = fmaxf(v, 0.f);
          if(outF) outF[(size_t)grow*HD + col] = v;
          else     outB[(size_t)grow*HD + col] = f2b(v);
        }
      }
    }
  }
}

extern "C" void kernel_launch(void* const* d_in, const int* in_sizes, int n_in,
                              void* d_out, int out_size, void* d_ws, size_t ws_size,
                              hipStream_t stream){
  const float* feat  = (const float*)d_in[0];
  const int*   etyp  = (const int*)  d_in[1];
  const float* ew    = (const float*)d_in[2];
  const int*   src   = (const int*)  d_in[3];
  const int*   dst   = (const int*)  d_in[4];
  const float* comp1 = (const float*)d_in[5];
  const float* V1    = (const float*)d_in[6];
  const float* bias1 = (const float*)d_in[7];
  const float* comp2 = (const float*)d_in[8];
  const float* V2    = (const float*)d_in[9];
  const float* bias2 = (const float*)d_in[10];
  float* out = (float*)d_out;

  char* p = (char*)d_ws;
  auto alloc = [&](size_t bytes)->char* {
    char* q = p; p += (bytes + 255) & ~(size_t)255; return q;
  };
  ushortT* Wt1   = (ushortT*)alloc((size_t)HD*NREL*HD*2);        // 256 KB
  ushortT* Wt2   = (ushortT*)alloc((size_t)HD*NREL*HD*2);        // 256 KB
  ushortT* Acat  = (ushortT*)alloc(((size_t)NBUCK*HD + 64*1024)*2); // 102.4MB +pad
  ushortT* xb    = (ushortT*)alloc((size_t)N_NODES*HD*2);        // 12.8 MB
  ushortT* hmid  = (ushortT*)alloc((size_t)N_NODES*HD*2);        // 12.8 MB
  int*   deg   = (int*)  alloc((size_t)NBUCK*4);
  int*   cur   = (int*)  alloc((size_t)NBUCK*4);                 // adjacent to deg
  int*   offs  = (int*)  alloc((size_t)NBUCK*4);
  int*   part1 = (int*)  alloc(2048*4);
  uint32_t* es = (uint32_t*)alloc((size_t)N_EDGES*4);            // 3.2 MB

  // ---- CSR build over 400k (dst,etype) buckets ----
  hipMemsetAsync(deg, 0, (size_t)2*NBUCK*4, stream);             // deg + cur
  k_hist<<<(N_EDGES+255)/256,256,0,stream>>>(dst,etyp,deg);
  int nb1 = (NBUCK+255)/256;          // 1563
  k_scan1<<<nb1,256,0,stream>>>(deg,offs,part1,NBUCK);
  k_scanmid<<<1,256,0,stream>>>(part1,nb1);
  k_scatter<<<(N_EDGES+255)/256,256,0,stream>>>(src,etyp,ew,dst,offs,part1,cur,es);

  // ---- fused prep: bf16 table + relation weights (both layers) ----
  k_prep<<<F2B_BLOCKS + 1024, 256, 0, stream>>>(feat,comp1,V1,comp2,V2,xb,Wt1,Wt2);

  int aggGrid  = NBUCK/16;                 // 25000 blocks: 4 waves x 4 buckets
  int gemmGrid = (N_NODES + GBM - 1)/GBM;  // 1563
  // ---- layer 1 ----
  k_agg<<<aggGrid,256,0,stream>>>(xb,   offs, part1, deg, es, Acat);
  k_gemm<<<gemmGrid,256,0,stream>>>(Acat, Wt1, bias1, nullptr, hmid, 1);
  // ---- layer 2 ----
  k_agg<<<aggGrid,256,0,stream>>>(hmid, offs, part1, deg, es, Acat);
  k_gemm<<<gemmGrid,256,0,stream>>>(Acat, Wt2, bias2, out, nullptr, 0);
}